// Round 8
// baseline (186.036 us; speedup 1.0000x reference)
//
#include <hip/hip_runtime.h>

// Problem constants (from setup_inputs)
constexpr int NROIS = 2000;
constexpr int Hh = 100, Ww = 100, Cc = 256;
constexpr int CH = 7, CW = 7;
constexpr int C4 = Cc / 4;               // 64 float4 per pixel -> one wave-width
constexpr int NPIX = NROIS * CH * CW;    // 98,000 output pixels
constexpr int PPW  = 4;                  // pixels per wave (16 loads in flight)
constexpr int PPB  = PPW * 4;            // 16 pixels per 256-thread block
constexpr int NBLK = NPIX / PPB;         // 6,125 blocks (exact)
constexpr int NXCD = 8;
constexpr int CHUNK_Q = NBLK / NXCD;     // 765
constexpr int CHUNK_R = NBLK % NXCD;     // 5

constexpr int ROW_BYTES = Ww * Cc * 4;            // 102,400 B per fm row
constexpr int PIX_BYTES = Cc * 4;                 // 1,024 B per fm pixel
constexpr int IMG_BYTES = Hh * ROW_BYTES;         // 10,240,000 B per image
constexpr int OUTROI_BYTES = CH * CW * PIX_BYTES; // 50,176 B per roi output

typedef float floatx4 __attribute__((ext_vector_type(4)));

// ---------------------------------------------------------------------------
// Prepass (1 block): counting-sort ROIs by (image, y-band) AND precompute all
// per-ROI parameters into params[sorted_slot]:
//   P[0]=y0 P[1]=sy P[2]=x0 P[3]=sx  (in_y = y0+i*sy, in_x = x0+j*sx, math
//   order mirrors the reference exactly)  P[4]=fm byte base  P[5]=out byte base
// ---------------------------------------------------------------------------
constexpr int NBUCKET = 64;   // 8 images x 8 y-bands

__global__ __launch_bounds__(256) void roi_prep_kernel(
    const float* __restrict__ rois, float* __restrict__ params)
{
    __shared__ int cnt[NBUCKET];
    __shared__ int offs[NBUCKET];
    int t = threadIdx.x;
    if (t < NBUCKET) cnt[t] = 0;
    __syncthreads();

    for (int n = t; n < NROIS; n += 256) {
        const float* r = rois + (size_t)n * 5;
        int   b    = (int)r[0];
        float cy   = 0.5f * (r[2] + r[4]);                 // pixel units [0,100]
        int   band = min(7, max(0, (int)(cy * 0.08f)));
        atomicAdd(&cnt[b * 8 + band], 1);
    }
    __syncthreads();
    if (t == 0) {
        int s = 0;
        for (int k = 0; k < NBUCKET; ++k) { offs[k] = s; s += cnt[k]; }
    }
    __syncthreads();
    for (int n = t; n < NROIS; n += 256) {
        const float* r = rois + (size_t)n * 5;
        int   b    = (int)r[0];
        float cy   = 0.5f * (r[2] + r[4]);
        int   band = min(7, max(0, (int)(cy * 0.08f)));
        int   pos  = atomicAdd(&offs[b * 8 + band], 1);

        // Reference math order: normalize by /W,/H (IEEE divide), then *(dim-1)
        float x1 = r[1] / (float)Ww;
        float y1 = r[2] / (float)Hh;
        float x2 = r[3] / (float)Ww;
        float y2 = r[4] / (float)Hh;
        float* P = params + (size_t)pos * 8;
        P[0] = y1 * (float)(Hh - 1);                          // y0
        P[1] = (y2 - y1) * (float)(Hh - 1) / (float)(CH - 1); // sy
        P[2] = x1 * (float)(Ww - 1);                          // x0
        P[3] = (x2 - x1) * (float)(Ww - 1) / (float)(CW - 1); // sx
        ((int*)P)[4] = b * IMG_BYTES;
        ((int*)P)[5] = n * OUTROI_BYTES;
    }
}

// ---------------------------------------------------------------------------
// Main kernel: ONE WAVE = FOUR OUTPUT PIXELS, all 16 bilinear gathers issued
// BEFORE any consumption.
// Theory being tested: R3-R7 all pinned at ~61-65 us because VGPR_Count=16
// forced the compiler to serialize the 4 gathers into dependent
// load->wait->consume epochs (~4 serial HBM round-trips per pixel; poison
// fills flush L2/L3 every iteration so every epoch is cold-HBM latency).
// Here: __launch_bounds__(256,4) raises the VGPR cap to 128; 16 distinct
// floatx4 destinations + sched_barrier(0) fence force ONE memory epoch per
// 4 pixels. Sort + XCD chunking + plain stores retained.
// ---------------------------------------------------------------------------
__global__ __launch_bounds__(256, 4) void roi_gather_kernel(
    const char* __restrict__ fm,      // [8,100,100,256] fp32 as bytes
    const float* __restrict__ params, // [2000][8] per sorted slot
    char* __restrict__ out)           // [2000,7,7,256] fp32 as bytes
{
    int blk  = blockIdx.x;
    int xcd  = blk & (NXCD - 1);
    int slot = blk >> 3;
    int work = (xcd < CHUNK_R ? xcd * (CHUNK_Q + 1)
                              : CHUNK_R * (CHUNK_Q + 1) + (xcd - CHUNK_R) * CHUNK_Q)
             + slot;

    // Wave-uniform base pixel id -> scalar
    int gbase = __builtin_amdgcn_readfirstlane(work * PPB + (threadIdx.x >> 6) * PPW);
    int lane  = threadIdx.x & (C4 - 1);
    unsigned laneoff = lane * 16;

    // ---- per-pixel setup (k = 0..3), all independent -----------------------
#define SETUP(k)                                                               \
    int g##k   = gbase + k;                                                    \
    int s##k   = g##k / 49;                                                    \
    int pix##k = g##k - s##k * 49;                                             \
    int i##k   = pix##k / 7;                                                   \
    int j##k   = pix##k - i##k * 7;                                            \
    const float* P##k = params + (size_t)s##k * 8;                             \
    float y0_##k = P##k[0], sy_##k = P##k[1];                                  \
    float x0_##k = P##k[2], sx_##k = P##k[3];                                  \
    int fmbase##k  = ((const int*)P##k)[4];                                    \
    int outbase##k = ((const int*)P##k)[5];                                    \
    float iny##k = y0_##k + (float)i##k * sy_##k;                              \
    float inx##k = x0_##k + (float)j##k * sx_##k;                              \
    bool valid##k = (iny##k >= 0.f) && (iny##k <= (float)(Hh - 1)) &&          \
                    (inx##k >= 0.f) && (inx##k <= (float)(Ww - 1));            \
    float fy##k = floorf(iny##k), fx##k = floorf(inx##k);                      \
    float ly##k = iny##k - fy##k, lx##k = inx##k - fx##k;                      \
    int ty##k = max(0, min(Hh - 1, (int)fy##k));                               \
    int by##k = max(0, min(Hh - 1, (int)ceilf(iny##k)));                       \
    int tx##k = max(0, min(Ww - 1, (int)fx##k));                               \
    int bx##k = max(0, min(Ww - 1, (int)ceilf(inx##k)));                       \
    unsigned rT##k = (unsigned)(fmbase##k + ty##k * ROW_BYTES) + laneoff;      \
    unsigned rB##k = (unsigned)(fmbase##k + by##k * ROW_BYTES) + laneoff;      \
    unsigned oT##k = (unsigned)(tx##k * PIX_BYTES);                            \
    unsigned oB##k = (unsigned)(bx##k * PIX_BYTES);

    SETUP(0) SETUP(1) SETUP(2) SETUP(3)
#undef SETUP

    // ---- issue ALL 16 gathers into distinct registers ----------------------
#define LDG(off) (*(const floatx4*)(fm + (off)))
    floatx4 tl0 = LDG(rT0 + oT0), tr0 = LDG(rT0 + oB0),
            bl0 = LDG(rB0 + oT0), br0 = LDG(rB0 + oB0);
    floatx4 tl1 = LDG(rT1 + oT1), tr1 = LDG(rT1 + oB1),
            bl1 = LDG(rB1 + oT1), br1 = LDG(rB1 + oB1);
    floatx4 tl2 = LDG(rT2 + oT2), tr2 = LDG(rT2 + oB2),
            bl2 = LDG(rB2 + oT2), br2 = LDG(rB2 + oB2);
    floatx4 tl3 = LDG(rT3 + oT3), tr3 = LDG(rT3 + oB3),
            bl3 = LDG(rB3 + oT3), br3 = LDG(rB3 + oB3);
#undef LDG
    // Fence: nothing below may be scheduled above this point, so all 16 loads
    // are issued before the first consuming waitcnt.
    __builtin_amdgcn_sched_barrier(0);

    // ---- consume (compiler inserts decreasing vmcnt waits) -----------------
#define FINISH(k)                                                              \
    {                                                                          \
        floatx4 top = tl##k + (tr##k - tl##k) * lx##k;                         \
        floatx4 bot = bl##k + (br##k - bl##k) * lx##k;                         \
        floatx4 o   = top + (bot - top) * ly##k;                               \
        o = valid##k ? o : (floatx4)0.f;                                       \
        *(floatx4*)(out + outbase##k + pix##k * PIX_BYTES + laneoff) = o;      \
    }
    FINISH(0) FINISH(1) FINISH(2) FINISH(3)
#undef FINISH
}

extern "C" void kernel_launch(void* const* d_in, const int* in_sizes, int n_in,
                              void* d_out, int out_size, void* d_ws, size_t ws_size,
                              hipStream_t stream) {
    const float* fm   = (const float*)d_in[0];   // [8,100,100,256] fp32
    const float* rois = (const float*)d_in[1];   // [2000,5] fp32
    char* out = (char*)d_out;                    // [2000,7,7,256] fp32
    float* params = (float*)d_ws;                // 2000*32 B = 64 KB workspace

    roi_prep_kernel<<<1, 256, 0, stream>>>(rois, params);
    roi_gather_kernel<<<NBLK, 256, 0, stream>>>((const char*)fm, params, out);
}

// Round 9
// 184.077 us; speedup vs baseline: 1.0106x; 1.0106x over previous
//
#include <hip/hip_runtime.h>

// Problem constants (from setup_inputs)
constexpr int NROIS = 2000;
constexpr int Hh = 100, Ww = 100, Cc = 256;
constexpr int CH = 7, CW = 7;
constexpr int C4 = Cc / 4;              // 64 float4 per pixel -> one wave-width
constexpr int NPIX = NROIS * CH * CW;   // 98,000 output pixels (1 wave each)
constexpr int WPB  = 4;                 // waves per block
constexpr int NBLK = NPIX / WPB;        // 24,500 blocks (exact)
constexpr int NXCD = 8;
constexpr int CHUNK_Q = NBLK / NXCD;    // 3062
constexpr int CHUNK_R = NBLK % NXCD;    // 4

constexpr int ROW_BYTES = Ww * Cc * 4;            // 102,400 B per fm row
constexpr int PIX_BYTES = Cc * 4;                 // 1,024 B per fm pixel
constexpr int IMG_BYTES = Hh * ROW_BYTES;         // 10,240,000 B per image
constexpr int OUTROI_BYTES = CH * CW * PIX_BYTES; // 50,176 B per roi output

typedef float floatx4 __attribute__((ext_vector_type(4)));

// Address-space-qualified pointer types for the global->LDS DMA builtin.
typedef const __attribute__((address_space(1))) void* gptr_t;
typedef __attribute__((address_space(3))) void*       lptr_t;
// size must be a literal 16 -> emits global_load_lds_dwordx4 (m97):
// lane i's 16B from (g)+16*i lands at LDS (l)+16*i (wave-uniform dest base).
#define GLOAD_LDS16(g, l) \
    __builtin_amdgcn_global_load_lds((gptr_t)(g), (lptr_t)(l), 16, 0, 0)

// ---------------------------------------------------------------------------
// Prepass (1 block): counting-sort ROIs by (image, y-band) AND precompute all
// per-ROI parameters into params[sorted_slot]:
//   P[0]=y0 P[1]=sy P[2]=x0 P[3]=sx  (in_y = y0+i*sy, in_x = x0+j*sx, math
//   order mirrors the reference exactly)  P[4]=fm byte base  P[5]=out byte base
// ---------------------------------------------------------------------------
constexpr int NBUCKET = 64;   // 8 images x 8 y-bands

__global__ __launch_bounds__(256) void roi_prep_kernel(
    const float* __restrict__ rois, float* __restrict__ params)
{
    __shared__ int cnt[NBUCKET];
    __shared__ int offs[NBUCKET];
    int t = threadIdx.x;
    if (t < NBUCKET) cnt[t] = 0;
    __syncthreads();

    for (int n = t; n < NROIS; n += 256) {
        const float* r = rois + (size_t)n * 5;
        int   b    = (int)r[0];
        float cy   = 0.5f * (r[2] + r[4]);                 // pixel units [0,100]
        int   band = min(7, max(0, (int)(cy * 0.08f)));
        atomicAdd(&cnt[b * 8 + band], 1);
    }
    __syncthreads();
    if (t == 0) {
        int s = 0;
        for (int k = 0; k < NBUCKET; ++k) { offs[k] = s; s += cnt[k]; }
    }
    __syncthreads();
    for (int n = t; n < NROIS; n += 256) {
        const float* r = rois + (size_t)n * 5;
        int   b    = (int)r[0];
        float cy   = 0.5f * (r[2] + r[4]);
        int   band = min(7, max(0, (int)(cy * 0.08f)));
        int   pos  = atomicAdd(&offs[b * 8 + band], 1);

        // Reference math order: normalize by /W,/H (IEEE divide), then *(dim-1)
        float x1 = r[1] / (float)Ww;
        float y1 = r[2] / (float)Hh;
        float x2 = r[3] / (float)Ww;
        float y2 = r[4] / (float)Hh;
        float* P = params + (size_t)pos * 8;
        P[0] = y1 * (float)(Hh - 1);                          // y0
        P[1] = (y2 - y1) * (float)(Hh - 1) / (float)(CH - 1); // sy
        P[2] = x1 * (float)(Ww - 1);                          // x0
        P[3] = (x2 - x1) * (float)(Ww - 1) / (float)(CW - 1); // sx
        ((int*)P)[4] = b * IMG_BYTES;
        ((int*)P)[5] = n * OUTROI_BYTES;
    }
}

// ---------------------------------------------------------------------------
// Main kernel: ONE WAVE PER OUTPUT PIXEL, gathers via the ASYNC DMA PATH.
// A/B vs R7 (61.5 us): the 4 bilinear gathers return to LDS via
// global_load_lds_dwordx4 instead of to VGPRs. Theory: R3-R8's invariant
// 61-65 us floor is a per-CU outstanding-miss-buffer limit on the VGPR
// return path (all throughput models sit 2-5x below measurement; only
// latency x concurrency fits). The DMA engine is the one untried hardware
// path. Each gather is wave-contiguous 1KB (lane*16) -> matches the DMA's
// wave-uniform-LDS-dest + lane*16 layout exactly.
// Sort + XCD chunking + plain stores retained from R7.
// ---------------------------------------------------------------------------
__global__ __launch_bounds__(256) void roi_gather_kernel(
    const char* __restrict__ fm,      // [8,100,100,256] fp32 as bytes
    const float* __restrict__ params, // [2000][8] per sorted slot
    char* __restrict__ out)           // [2000,7,7,256] fp32 as bytes
{
    __shared__ char ldsbuf[WPB][4096];   // 4KB per wave: tl|tr|bl|br

    int blk  = blockIdx.x;
    int xcd  = blk & (NXCD - 1);
    int slot = blk >> 3;
    int work = (xcd < CHUNK_R ? xcd * (CHUNK_Q + 1)
                              : CHUNK_R * (CHUNK_Q + 1) + (xcd - CHUNK_R) * CHUNK_Q)
             + slot;

    int wv   = threadIdx.x >> 6;
    int g    = __builtin_amdgcn_readfirstlane(work * WPB + wv);
    int lane = threadIdx.x & (C4 - 1);
    unsigned laneoff = lane * 16;

    int s   = g / 49;            // sorted roi slot (magic-mul div)
    int pix = g - s * 49;
    int i   = pix / 7;
    int j   = pix - i * 7;

    const float* P = params + (size_t)s * 8;
    float y0 = P[0], sy = P[1], x0 = P[2], sx = P[3];
    int fmbase  = ((const int*)P)[4];
    int outbase = ((const int*)P)[5];

    float in_y = y0 + (float)i * sy;
    float in_x = x0 + (float)j * sx;

    bool valid = (in_y >= 0.f) && (in_y <= (float)(Hh - 1)) &&
                 (in_x >= 0.f) && (in_x <= (float)(Ww - 1));

    float fy = floorf(in_y), fx = floorf(in_x);
    float ly = in_y - fy,    lx = in_x - fx;
    int ty = max(0, min(Hh - 1, (int)fy));
    int by = max(0, min(Hh - 1, (int)ceilf(in_y)));
    int tx = max(0, min(Ww - 1, (int)fx));
    int bx = max(0, min(Ww - 1, (int)ceilf(in_x)));

    unsigned rT = (unsigned)(fmbase + ty * ROW_BYTES) + laneoff;
    unsigned rB = (unsigned)(fmbase + by * ROW_BYTES) + laneoff;
    unsigned oTX = (unsigned)(tx * PIX_BYTES);
    unsigned oBX = (unsigned)(bx * PIX_BYTES);

    char* lb = &ldsbuf[wv][0];   // wave-private region; no cross-wave sharing

    // Issue all 4 DMA gathers (1KB each), then a single drain.
    GLOAD_LDS16(fm + rT + oTX, lb);
    GLOAD_LDS16(fm + rT + oBX, lb + 1024);
    GLOAD_LDS16(fm + rB + oTX, lb + 2048);
    GLOAD_LDS16(fm + rB + oBX, lb + 3072);
    asm volatile("s_waitcnt vmcnt(0)" ::: "memory");
    __builtin_amdgcn_sched_barrier(0);

    // Read back own 16B slices (2-way bank aliasing = free).
    floatx4 tl = *(const floatx4*)(lb + laneoff);
    floatx4 tr = *(const floatx4*)(lb + laneoff + 1024);
    floatx4 bl = *(const floatx4*)(lb + laneoff + 2048);
    floatx4 br = *(const floatx4*)(lb + laneoff + 3072);

    floatx4 top = tl + (tr - tl) * lx;
    floatx4 bot = bl + (br - bl) * lx;
    floatx4 o   = top + (bot - top) * ly;
    o = valid ? o : (floatx4)0.f;

    *(floatx4*)(out + outbase + pix * PIX_BYTES + laneoff) = o;
}

extern "C" void kernel_launch(void* const* d_in, const int* in_sizes, int n_in,
                              void* d_out, int out_size, void* d_ws, size_t ws_size,
                              hipStream_t stream) {
    const float* fm   = (const float*)d_in[0];   // [8,100,100,256] fp32
    const float* rois = (const float*)d_in[1];   // [2000,5] fp32
    char* out = (char*)d_out;                    // [2000,7,7,256] fp32
    float* params = (float*)d_ws;                // 2000*32 B = 64 KB workspace

    roi_prep_kernel<<<1, 256, 0, stream>>>(rois, params);
    roi_gather_kernel<<<NBLK, 256, 0, stream>>>((const char*)fm, params, out);
}